// Round 1
// baseline (806.483 us; speedup 1.0000x reference)
//
#include <hip/hip_runtime.h>
#include <hip/hip_bf16.h>
#include <math.h>

#define N_NODES 100000
#define N_EDGES 1600000
#define HID 128
#define D_IN 6
#define NEG_SLOPE 0.2f

// ---------------------------------------------------------------------------
// K1: per-node: h = x @ w_gat ; a_src = h.att_src ; a_dst = h.att_dst
// one 128-thread block per node
__global__ __launch_bounds__(128) void k_node(
    const float* __restrict__ x, const float* __restrict__ w_gat,
    const float* __restrict__ att_src, const float* __restrict__ att_dst,
    float* __restrict__ h, float* __restrict__ a_src, float* __restrict__ a_dst)
{
    int n = blockIdx.x;
    int k = threadIdx.x;
    float xr[D_IN];
#pragma unroll
    for (int i = 0; i < D_IN; ++i) xr[i] = x[n * D_IN + i];
    float acc = 0.f;
#pragma unroll
    for (int i = 0; i < D_IN; ++i) acc += xr[i] * w_gat[i * HID + k];
    h[n * HID + k] = acc;

    float v1 = acc * att_src[k];
    float v2 = acc * att_dst[k];
    for (int o = 32; o > 0; o >>= 1) {
        v1 += __shfl_down(v1, o);
        v2 += __shfl_down(v2, o);
    }
    __shared__ float red[4];
    if ((threadIdx.x & 63) == 0) {
        int w = threadIdx.x >> 6;
        red[w * 2 + 0] = v1;
        red[w * 2 + 1] = v2;
    }
    __syncthreads();
    if (threadIdx.x == 0) {
        a_src[n] = red[0] + red[2];
        a_dst[n] = red[1] + red[3];
    }
}

// ---------------------------------------------------------------------------
// K_dot: dotwe = sum_k w_edge[k]*att_edge[k]
__global__ __launch_bounds__(128) void k_dot(
    const float* __restrict__ w_edge, const float* __restrict__ att_edge,
    float* __restrict__ dotwe)
{
    int tid = threadIdx.x;
    float v = w_edge[tid] * att_edge[tid];
    for (int o = 32; o > 0; o >>= 1) v += __shfl_down(v, o);
    __shared__ float red[2];
    if ((tid & 63) == 0) red[tid >> 6] = v;
    __syncthreads();
    if (tid == 0) dotwe[0] = red[0] + red[1];
}

// ---------------------------------------------------------------------------
// K2: in-degree count
__global__ __launch_bounds__(256) void k_count(
    const int* __restrict__ dst, int* __restrict__ cnt)
{
    int e = blockIdx.x * 256 + threadIdx.x;
    if (e < N_EDGES) atomicAdd(&cnt[dst[e]], 1);
}

// ---------------------------------------------------------------------------
// scan: exclusive prefix sum of cnt[N] -> off[N+1]
__global__ __launch_bounds__(256) void k_scan1(
    const int* __restrict__ cnt, int* __restrict__ incl, int* __restrict__ bsums)
{
    __shared__ int s[256];
    int tid = threadIdx.x;
    int i = blockIdx.x * 256 + tid;
    int v = (i < N_NODES) ? cnt[i] : 0;
    s[tid] = v;
    __syncthreads();
    for (int o = 1; o < 256; o <<= 1) {
        int t = (tid >= o) ? s[tid - o] : 0;
        __syncthreads();
        s[tid] += t;
        __syncthreads();
    }
    if (i < N_NODES) incl[i] = s[tid];
    if (tid == 255) bsums[blockIdx.x] = s[255];
}

__global__ __launch_bounds__(512) void k_scan2(
    const int* __restrict__ bsums, int* __restrict__ boffs, int nb)
{
    __shared__ int s[512];
    int tid = threadIdx.x;
    int v = (tid < nb) ? bsums[tid] : 0;
    s[tid] = v;
    __syncthreads();
    for (int o = 1; o < 512; o <<= 1) {
        int t = (tid >= o) ? s[tid - o] : 0;
        __syncthreads();
        s[tid] += t;
        __syncthreads();
    }
    if (tid < nb) boffs[tid] = s[tid] - v;  // exclusive
}

__global__ __launch_bounds__(256) void k_scan3(
    const int* __restrict__ cnt, const int* __restrict__ incl,
    const int* __restrict__ boffs, int* __restrict__ off)
{
    int i = blockIdx.x * 256 + threadIdx.x;
    if (i < N_NODES) {
        int b = boffs[blockIdx.x];
        off[i] = b + incl[i] - cnt[i];
        if (i == N_NODES - 1) off[N_NODES] = b + incl[i];
    }
}

// ---------------------------------------------------------------------------
// K4: scatter edges into dst-sorted order; compute leaky-relu logits on the fly
__global__ __launch_bounds__(256) void k_scatter(
    const int* __restrict__ src, const int* __restrict__ dst,
    const float* __restrict__ ew, const float* __restrict__ a_src,
    const float* __restrict__ a_dst, const float* __restrict__ dotwe,
    const int* __restrict__ off, int* __restrict__ fill,
    int* __restrict__ src_srt, int* __restrict__ eid_srt,
    float* __restrict__ logit_srt)
{
    int e = blockIdx.x * 256 + threadIdx.x;
    if (e >= N_EDGES) return;
    float dw = dotwe[0];
    int d = dst[e];
    int s = src[e];
    float l = a_src[s] + a_dst[d] + ew[e] * dw;
    l = (l >= 0.f) ? l : NEG_SLOPE * l;
    int pos = off[d] + atomicAdd(&fill[d], 1);
    src_srt[pos] = s;
    eid_srt[pos] = e;
    logit_srt[pos] = l;
}

// ---------------------------------------------------------------------------
// K5: per-dst-node segment softmax + GAT aggregation + bias + relu
// one 128-thread block per node
__global__ __launch_bounds__(128) void k_gat(
    const int* __restrict__ src_srt, const int* __restrict__ eid_srt,
    const float* __restrict__ logit_srt, const int* __restrict__ off,
    const float* __restrict__ h, const float* __restrict__ b_gat,
    float* __restrict__ alpha_srt, float* __restrict__ alpha_out,
    float* __restrict__ dinv, float* __restrict__ h1)
{
    int n = blockIdx.x;
    int tid = threadIdx.x;
    int beg = off[n], end = off[n + 1];
    __shared__ float red[2];

    // --- segment max ---
    float m = -INFINITY;
    for (int j = beg + tid; j < end; j += 128) m = fmaxf(m, logit_srt[j]);
    for (int o = 32; o > 0; o >>= 1) m = fmaxf(m, __shfl_down(m, o));
    if ((tid & 63) == 0) red[tid >> 6] = m;
    __syncthreads();
    float mall = fmaxf(red[0], red[1]);
    __syncthreads();

    // --- exp + segment sum ---
    float ps = 0.f;
    for (int j = beg + tid; j < end; j += 128) {
        float p = expf(logit_srt[j] - mall);
        alpha_srt[j] = p;
        ps += p;
    }
    for (int o = 32; o > 0; o >>= 1) ps += __shfl_down(ps, o);
    if ((tid & 63) == 0) red[tid >> 6] = ps;
    __syncthreads();
    float denom = red[0] + red[1];
    __syncthreads();
    float scale = 1.0f / fmaxf(denom, 1e-16f);

    // --- normalize, write alpha (sorted + original order), deg ---
    float dsum = 0.f;
    for (int j = beg + tid; j < end; j += 128) {
        float a = alpha_srt[j] * scale;
        alpha_srt[j] = a;
        alpha_out[eid_srt[j]] = a;
        dsum += a;
    }
    for (int o = 32; o > 0; o >>= 1) dsum += __shfl_down(dsum, o);
    if ((tid & 63) == 0) red[tid >> 6] = dsum;
    __syncthreads();
    float deg = red[0] + red[1];
    if (tid == 0) dinv[n] = (deg > 0.f) ? 1.0f / sqrtf(deg) : 0.0f;
    __syncthreads();  // alpha_srt global writes visible block-wide

    // --- aggregate: h1[n,:] = relu(sum_j alpha_j * h[src_j,:] + b_gat) ---
    float acc = 0.f;
    for (int j = beg; j < end; ++j) {
        int s = src_srt[j];
        float a = alpha_srt[j];
        acc += a * h[s * HID + tid];
    }
    h1[n * HID + tid] = fmaxf(acc + b_gat[tid], 0.0f);
}

// ---------------------------------------------------------------------------
// K6: hx = h1 @ w_gcn  (f32 vector GEMM, 32 nodes per 128-thread block)
#define NPB 32
__global__ __launch_bounds__(128) void k_gemm(
    const float* __restrict__ h1, const float* __restrict__ w,
    float* __restrict__ hx)
{
    __shared__ float hs[NPB][HID];
    int n0 = blockIdx.x * NPB;
    int tid = threadIdx.x;
#pragma unroll
    for (int r = 0; r < NPB; ++r) hs[r][tid] = h1[(n0 + r) * HID + tid];
    __syncthreads();
    float acc[NPB];
#pragma unroll
    for (int r = 0; r < NPB; ++r) acc[r] = 0.f;
#pragma unroll 4
    for (int i = 0; i < HID; ++i) {
        float wv = w[i * HID + tid];
#pragma unroll
        for (int r = 0; r < NPB; ++r) acc[r] += hs[r][i] * wv;
    }
#pragma unroll
    for (int r = 0; r < NPB; ++r) hx[(n0 + r) * HID + tid] = acc[r];
}

// ---------------------------------------------------------------------------
// K7: GCN aggregation with norm = dinv[src]*alpha*dinv[dst], bias, relu,
//     fused output head out[n,0:2] = h2 . w_out + b_out
__global__ __launch_bounds__(128) void k_gcn(
    const int* __restrict__ src_srt, const int* __restrict__ off,
    const float* __restrict__ alpha_srt, const float* __restrict__ dinv,
    const float* __restrict__ hx, const float* __restrict__ b_gcn,
    const float* __restrict__ w_out, const float* __restrict__ b_out,
    float* __restrict__ out)
{
    int n = blockIdx.x;
    int tid = threadIdx.x;
    int beg = off[n], end = off[n + 1];
    float dn = dinv[n];
    float acc = 0.f;
    for (int j = beg; j < end; ++j) {
        int s = src_srt[j];
        float nm = dinv[s] * alpha_srt[j] * dn;
        acc += nm * hx[s * HID + tid];
    }
    float h2 = fmaxf(acc + b_gcn[tid], 0.0f);
    float v0 = h2 * w_out[tid * 2 + 0];
    float v1 = h2 * w_out[tid * 2 + 1];
    for (int o = 32; o > 0; o >>= 1) {
        v0 += __shfl_down(v0, o);
        v1 += __shfl_down(v1, o);
    }
    __shared__ float red[4];
    if ((tid & 63) == 0) {
        int w = tid >> 6;
        red[w * 2 + 0] = v0;
        red[w * 2 + 1] = v1;
    }
    __syncthreads();
    if (tid == 0) {
        out[n * 2 + 0] = red[0] + red[2] + b_out[0];
        out[n * 2 + 1] = red[1] + red[3] + b_out[1];
    }
}

// ---------------------------------------------------------------------------
// K8: copy edge_index (int) into output as float
__global__ __launch_bounds__(256) void k_copy_ei(
    const int* __restrict__ ei, float* __restrict__ out_ei)
{
    int i = blockIdx.x * 256 + threadIdx.x;
    if (i < 2 * N_EDGES) out_ei[i] = (float)ei[i];
}

// ---------------------------------------------------------------------------
extern "C" void kernel_launch(void* const* d_in, const int* in_sizes, int n_in,
                              void* d_out, int out_size, void* d_ws, size_t ws_size,
                              hipStream_t stream)
{
    // inputs in setup_inputs() dict order
    const float* x        = (const float*)d_in[0];
    const int*   ei       = (const int*)d_in[1];   // [2,E]: src=ei[0:E], dst=ei[E:2E]
    const float* ew       = (const float*)d_in[2];
    const float* w_gat    = (const float*)d_in[3];
    const float* att_src  = (const float*)d_in[4];
    const float* att_dst  = (const float*)d_in[5];
    const float* w_edge   = (const float*)d_in[6];
    const float* att_edge = (const float*)d_in[7];
    const float* b_gat    = (const float*)d_in[8];
    const float* w_gcn    = (const float*)d_in[9];
    const float* b_gcn    = (const float*)d_in[10];
    const float* w_out    = (const float*)d_in[11];
    const float* b_out    = (const float*)d_in[12];

    const int* src = ei;
    const int* dst = ei + N_EDGES;

    // output layout: out[N*2] | edge_index[2E] as float | alpha[E]
    float* out_head  = (float*)d_out;
    float* out_ei    = out_head + 2 * N_NODES;
    float* out_alpha = out_ei + 2 * N_EDGES;

    // workspace carve-up
    char* ws = (char*)d_ws;
    size_t o = 0;
    auto alloc = [&](size_t bytes) -> char* {
        char* p = ws + o;
        o = (o + bytes + 255) & ~(size_t)255;
        return p;
    };
    float* h         = (float*)alloc((size_t)N_NODES * HID * 4);
    float* h1        = (float*)alloc((size_t)N_NODES * HID * 4);
    float* hx        = h;  // alias: h dead after k_gat
    float* a_src     = (float*)alloc(N_NODES * 4);
    float* a_dst     = (float*)alloc(N_NODES * 4);
    float* dinv      = (float*)alloc(N_NODES * 4);
    int*   cnt       = (int*)alloc(N_NODES * 4);
    int*   incl      = (int*)alloc(N_NODES * 4);
    int*   off       = (int*)alloc((N_NODES + 1) * 4);
    int*   fill      = (int*)alloc(N_NODES * 4);
    int*   bsums     = (int*)alloc(512 * 4);
    int*   boffs     = (int*)alloc(512 * 4);
    int*   src_srt   = (int*)alloc((size_t)N_EDGES * 4);
    int*   eid_srt   = (int*)alloc((size_t)N_EDGES * 4);
    float* logit_srt = (float*)alloc((size_t)N_EDGES * 4);
    float* alpha_srt = (float*)alloc((size_t)N_EDGES * 4);
    float* dotwe     = (float*)alloc(4);
    (void)ws_size; (void)out_size; (void)n_in; (void)in_sizes;

    hipMemsetAsync(cnt, 0, N_NODES * 4, stream);
    hipMemsetAsync(fill, 0, N_NODES * 4, stream);

    const int NB_SCAN = (N_NODES + 255) / 256;  // 391

    k_node<<<N_NODES, 128, 0, stream>>>(x, w_gat, att_src, att_dst, h, a_src, a_dst);
    k_dot<<<1, 128, 0, stream>>>(w_edge, att_edge, dotwe);
    k_count<<<(N_EDGES + 255) / 256, 256, 0, stream>>>(dst, cnt);
    k_scan1<<<NB_SCAN, 256, 0, stream>>>(cnt, incl, bsums);
    k_scan2<<<1, 512, 0, stream>>>(bsums, boffs, NB_SCAN);
    k_scan3<<<NB_SCAN, 256, 0, stream>>>(cnt, incl, boffs, off);
    k_scatter<<<(N_EDGES + 255) / 256, 256, 0, stream>>>(
        src, dst, ew, a_src, a_dst, dotwe, off, fill, src_srt, eid_srt, logit_srt);
    k_gat<<<N_NODES, 128, 0, stream>>>(
        src_srt, eid_srt, logit_srt, off, h, b_gat, alpha_srt, out_alpha, dinv, h1);
    k_gemm<<<N_NODES / NPB, 128, 0, stream>>>(h1, w_gcn, hx);
    k_gcn<<<N_NODES, 128, 0, stream>>>(
        src_srt, off, alpha_srt, dinv, hx, b_gcn, w_out, b_out, out_head);
    k_copy_ei<<<(2 * N_EDGES + 255) / 256, 256, 0, stream>>>(ei, out_ei);
}

// Round 2
// 569.352 us; speedup vs baseline: 1.4165x; 1.4165x over previous
//
#include <hip/hip_runtime.h>
#include <hip/hip_bf16.h>
#include <math.h>

#define N_NODES 100000
#define N_EDGES 1600000
#define HID 128
#define D_IN 6
#define NEG_SLOPE 0.2f

// ---------------------------------------------------------------------------
// K_prep (1 block, 128 thr): w_as = w_gat@att_src (6), w_ad = w_gat@att_dst (6),
// dotwe = w_edge . att_edge
__global__ __launch_bounds__(128) void k_prep(
    const float* __restrict__ w_gat, const float* __restrict__ att_src,
    const float* __restrict__ att_dst, const float* __restrict__ w_edge,
    const float* __restrict__ att_edge, float* __restrict__ w_as,
    float* __restrict__ w_ad, float* __restrict__ dotwe)
{
    int tid = threadIdx.x;
    __shared__ float red[4];
    float as = att_src[tid], ad = att_dst[tid];

    float v = w_edge[tid] * att_edge[tid];
    for (int o = 32; o; o >>= 1) v += __shfl_down(v, o);
    if ((tid & 63) == 0) red[tid >> 6] = v;
    __syncthreads();
    if (tid == 0) dotwe[0] = red[0] + red[1];

#pragma unroll
    for (int i = 0; i < D_IN; ++i) {
        float wv = w_gat[i * HID + tid];
        float v1 = wv * as, v2 = wv * ad;
        for (int o = 32; o; o >>= 1) {
            v1 += __shfl_down(v1, o);
            v2 += __shfl_down(v2, o);
        }
        __syncthreads();   // previous red consumers done
        if ((tid & 63) == 0) { red[(tid >> 6) * 2] = v1; red[(tid >> 6) * 2 + 1] = v2; }
        __syncthreads();
        if (tid == 0) { w_as[i] = red[0] + red[2]; w_ad[i] = red[1] + red[3]; }
    }
}

// ---------------------------------------------------------------------------
// K_asrc: a_src[n] = x[n].w_as ; a_dst[n] = x[n].w_ad
__global__ __launch_bounds__(256) void k_asrc(
    const float* __restrict__ x, const float* __restrict__ w_as,
    const float* __restrict__ w_ad, float* __restrict__ a_src,
    float* __restrict__ a_dst)
{
    int n = blockIdx.x * 256 + threadIdx.x;
    if (n >= N_NODES) return;
    float s0 = 0.f, s1 = 0.f;
#pragma unroll
    for (int i = 0; i < D_IN; ++i) {
        float xv = x[n * D_IN + i];
        s0 += xv * w_as[i];
        s1 += xv * w_ad[i];
    }
    a_src[n] = s0;
    a_dst[n] = s1;
}

// ---------------------------------------------------------------------------
// K_count: in-degree
__global__ __launch_bounds__(256) void k_count(
    const int* __restrict__ dst, int* __restrict__ cnt)
{
    int e = blockIdx.x * 256 + threadIdx.x;
    if (e < N_EDGES) atomicAdd(&cnt[dst[e]], 1);
}

// ---------------------------------------------------------------------------
// exclusive prefix sum of cnt[N] -> off[N+1]
__global__ __launch_bounds__(256) void k_scan1(
    const int* __restrict__ cnt, int* __restrict__ incl, int* __restrict__ bsums)
{
    __shared__ int s[256];
    int tid = threadIdx.x;
    int i = blockIdx.x * 256 + tid;
    int v = (i < N_NODES) ? cnt[i] : 0;
    s[tid] = v;
    __syncthreads();
    for (int o = 1; o < 256; o <<= 1) {
        int t = (tid >= o) ? s[tid - o] : 0;
        __syncthreads();
        s[tid] += t;
        __syncthreads();
    }
    if (i < N_NODES) incl[i] = s[tid];
    if (tid == 255) bsums[blockIdx.x] = s[255];
}

__global__ __launch_bounds__(512) void k_scan2(
    const int* __restrict__ bsums, int* __restrict__ boffs, int nb)
{
    __shared__ int s[512];
    int tid = threadIdx.x;
    int v = (tid < nb) ? bsums[tid] : 0;
    s[tid] = v;
    __syncthreads();
    for (int o = 1; o < 512; o <<= 1) {
        int t = (tid >= o) ? s[tid - o] : 0;
        __syncthreads();
        s[tid] += t;
        __syncthreads();
    }
    if (tid < nb) boffs[tid] = s[tid] - v;  // exclusive
}

__global__ __launch_bounds__(256) void k_scan3(
    const int* __restrict__ cnt, const int* __restrict__ incl,
    const int* __restrict__ boffs, int* __restrict__ off)
{
    int i = blockIdx.x * 256 + threadIdx.x;
    if (i < N_NODES) {
        int b = boffs[blockIdx.x];
        off[i] = b + incl[i] - cnt[i];
        if (i == N_NODES - 1) off[N_NODES] = b + incl[i];
    }
}

// ---------------------------------------------------------------------------
// K_scatter: dst-sorted edge list + leaky-relu logits
__global__ __launch_bounds__(256) void k_scatter(
    const int* __restrict__ src, const int* __restrict__ dst,
    const float* __restrict__ ew, const float* __restrict__ a_src,
    const float* __restrict__ a_dst, const float* __restrict__ dotwe,
    const int* __restrict__ off, int* __restrict__ fill,
    int* __restrict__ src_srt, int* __restrict__ eid_srt,
    float* __restrict__ logit_srt)
{
    int e = blockIdx.x * 256 + threadIdx.x;
    if (e >= N_EDGES) return;
    float dw = dotwe[0];
    int d = dst[e];
    int s = src[e];
    float l = a_src[s] + a_dst[d] + ew[e] * dw;
    l = (l >= 0.f) ? l : NEG_SLOPE * l;
    int pos = off[d] + atomicAdd(&fill[d], 1);
    src_srt[pos] = s;
    eid_srt[pos] = e;
    logit_srt[pos] = l;
}

// ---------------------------------------------------------------------------
// K_soft: per-dst segment softmax + 6-dim x aggregation.
// one 64-lane wave per node, 4 nodes per 256-thread block
__global__ __launch_bounds__(256) void k_soft(
    const int* __restrict__ src_srt, const int* __restrict__ eid_srt,
    const float* __restrict__ logit_srt, const int* __restrict__ off,
    const float* __restrict__ x, float* __restrict__ alpha_srt,
    float* __restrict__ alpha_out, float* __restrict__ dinv,
    float* __restrict__ xagg)
{
    int n = blockIdx.x * 4 + (threadIdx.x >> 6);
    int l = threadIdx.x & 63;
    int beg = off[n], end = off[n + 1];

    // segment max
    float m = -INFINITY;
    for (int j = beg + l; j < end; j += 64) m = fmaxf(m, logit_srt[j]);
    for (int o = 32; o; o >>= 1) m = fmaxf(m, __shfl_xor(m, o));

    // exp + sum
    float ps = 0.f;
    for (int j = beg + l; j < end; j += 64) {
        float p = expf(logit_srt[j] - m);
        alpha_srt[j] = p;
        ps += p;
    }
    for (int o = 32; o; o >>= 1) ps += __shfl_xor(ps, o);
    float scale = 1.0f / fmaxf(ps, 1e-16f);

    // normalize + alpha outputs + 6-dim weighted x gather
    float dsum = 0.f;
    float ax0 = 0.f, ax1 = 0.f, ax2 = 0.f, ax3 = 0.f, ax4 = 0.f, ax5 = 0.f;
    for (int j = beg + l; j < end; j += 64) {
        float a = alpha_srt[j] * scale;
        alpha_srt[j] = a;
        alpha_out[eid_srt[j]] = a;
        dsum += a;
        int s = src_srt[j];
        const float2* xp = (const float2*)(x + s * D_IN);
        float2 p0 = xp[0], p1 = xp[1], p2 = xp[2];
        ax0 += a * p0.x; ax1 += a * p0.y;
        ax2 += a * p1.x; ax3 += a * p1.y;
        ax4 += a * p2.x; ax5 += a * p2.y;
    }
    for (int o = 32; o; o >>= 1) {
        dsum += __shfl_xor(dsum, o);
        ax0 += __shfl_xor(ax0, o); ax1 += __shfl_xor(ax1, o);
        ax2 += __shfl_xor(ax2, o); ax3 += __shfl_xor(ax3, o);
        ax4 += __shfl_xor(ax4, o); ax5 += __shfl_xor(ax5, o);
    }
    if (l == 0) {
        dinv[n] = (dsum > 0.f) ? (1.0f / sqrtf(dsum)) : 0.0f;
        float* xo = xagg + n * D_IN;
        xo[0] = ax0; xo[1] = ax1; xo[2] = ax2;
        xo[3] = ax3; xo[4] = ax4; xo[5] = ax5;
    }
}

// ---------------------------------------------------------------------------
// K_gcn_gather: agg[n,:] = sum_j norm_j * relu(xagg[src_j] @ w_gat + b_gat)
// h1 recomputed per edge from 6-dim xagg (24B gather, L2-resident) instead of
// gathering a 512B h1 row. 8 edge-groups x 32 lanes, float4 over HID.
__global__ __launch_bounds__(256) void k_gcn_gather(
    const int* __restrict__ src_srt, const int* __restrict__ off,
    const float* __restrict__ alpha_srt, const float* __restrict__ dinv,
    const float* __restrict__ xagg, const float* __restrict__ w_gat,
    const float* __restrict__ b_gat, float* __restrict__ agg)
{
    int n = blockIdx.x;
    int tid = threadIdx.x;
    int g = tid >> 5;        // edge group 0..7
    int l = tid & 31;        // feature block (4 floats)

    float4 wg[D_IN];
#pragma unroll
    for (int i = 0; i < D_IN; ++i) wg[i] = *(const float4*)(w_gat + i * HID + 4 * l);
    float4 bg = *(const float4*)(b_gat + 4 * l);

    int beg = off[n], end = off[n + 1];
    float dn = dinv[n];
    float4 acc = {0.f, 0.f, 0.f, 0.f};

    for (int j = beg + g; j < end; j += 8) {
        int s = src_srt[j];
        float nm = dinv[s] * alpha_srt[j] * dn;
        const float2* xp = (const float2*)(xagg + s * D_IN);
        float2 p0 = xp[0], p1 = xp[1], p2 = xp[2];
        float4 h = bg;
        h.x += p0.x*wg[0].x + p0.y*wg[1].x + p1.x*wg[2].x + p1.y*wg[3].x + p2.x*wg[4].x + p2.y*wg[5].x;
        h.y += p0.x*wg[0].y + p0.y*wg[1].y + p1.x*wg[2].y + p1.y*wg[3].y + p2.x*wg[4].y + p2.y*wg[5].y;
        h.z += p0.x*wg[0].z + p0.y*wg[1].z + p1.x*wg[2].z + p1.y*wg[3].z + p2.x*wg[4].z + p2.y*wg[5].z;
        h.w += p0.x*wg[0].w + p0.y*wg[1].w + p1.x*wg[2].w + p1.y*wg[3].w + p2.x*wg[4].w + p2.y*wg[5].w;
        h.x = fmaxf(h.x, 0.f); h.y = fmaxf(h.y, 0.f);
        h.z = fmaxf(h.z, 0.f); h.w = fmaxf(h.w, 0.f);
        acc.x += nm * h.x; acc.y += nm * h.y;
        acc.z += nm * h.z; acc.w += nm * h.w;
    }

    // reduce the 2 groups within each wave
    acc.x += __shfl_xor(acc.x, 32); acc.y += __shfl_xor(acc.y, 32);
    acc.z += __shfl_xor(acc.z, 32); acc.w += __shfl_xor(acc.w, 32);

    __shared__ float4 lds[4][32];
    int w = tid >> 6;
    if ((tid & 63) < 32) lds[w][l] = acc;
    __syncthreads();
    if (tid < 32) {
        float4 a0 = lds[0][tid], a1 = lds[1][tid], a2 = lds[2][tid], a3 = lds[3][tid];
        float4 r;
        r.x = a0.x + a1.x + a2.x + a3.x;
        r.y = a0.y + a1.y + a2.y + a3.y;
        r.z = a0.z + a1.z + a2.z + a3.z;
        r.w = a0.w + a1.w + a2.w + a3.w;
        *(float4*)(agg + (size_t)n * HID + 4 * tid) = r;
    }
}

// ---------------------------------------------------------------------------
// K_dense2: h2 = relu(agg @ w_gcn + b_gcn); out = h2 @ w_out + b_out
// 32 nodes per 128-thread block; agg tile transposed in LDS (stride 36 -> no
// broadcast-read conflicts, distinct banks in the reduction phase).
#define NPB 32
#define HSTR (NPB + 4)
__global__ __launch_bounds__(128) void k_dense2(
    const float* __restrict__ agg, const float* __restrict__ w_gcn,
    const float* __restrict__ b_gcn, const float* __restrict__ w_out,
    const float* __restrict__ b_out, float* __restrict__ out)
{
    __shared__ float hsT[HID][HSTR];
    __shared__ float red[2][64];
    int n0 = blockIdx.x * NPB;
    int tid = threadIdx.x;

#pragma unroll
    for (int r = 0; r < NPB; ++r)
        hsT[tid][r] = agg[(size_t)(n0 + r) * HID + tid];
    __syncthreads();

    float acc[NPB];
#pragma unroll
    for (int r = 0; r < NPB; ++r) acc[r] = 0.f;
    for (int i = 0; i < HID; ++i) {
        float wv = w_gcn[i * HID + tid];
        const float4* hp = (const float4*)&hsT[i][0];
#pragma unroll
        for (int r4 = 0; r4 < NPB / 4; ++r4) {
            float4 hv = hp[r4];
            acc[r4 * 4 + 0] += hv.x * wv;
            acc[r4 * 4 + 1] += hv.y * wv;
            acc[r4 * 4 + 2] += hv.z * wv;
            acc[r4 * 4 + 3] += hv.w * wv;
        }
    }
    __syncthreads();

    float b = b_gcn[tid];
#pragma unroll
    for (int r = 0; r < NPB; ++r)
        hsT[tid][r] = fmaxf(acc[r] + b, 0.f);   // h2, transposed
    __syncthreads();

    // out[n0+r][o] = sum_k h2[k][r] * w_out[k*2+o] + b_out[o]
    int r = tid & 31, o = (tid >> 5) & 1, half = tid >> 6;
    float v = 0.f;
    for (int k = half * 64; k < half * 64 + 64; ++k)
        v += hsT[k][r] * w_out[k * 2 + o];
    red[half][tid & 63] = v;
    __syncthreads();
    if (tid < 64) {
        float t = red[0][tid] + red[1][tid];
        int rr = tid & 31, oo = tid >> 5;
        out[(size_t)(n0 + rr) * 2 + oo] = t + b_out[oo];
    }
}

// ---------------------------------------------------------------------------
// K_copy_ei: edge_index (int) -> float output
__global__ __launch_bounds__(256) void k_copy_ei(
    const int* __restrict__ ei, float* __restrict__ out_ei)
{
    int i = blockIdx.x * 256 + threadIdx.x;
    if (i < 2 * N_EDGES) out_ei[i] = (float)ei[i];
}

// ---------------------------------------------------------------------------
extern "C" void kernel_launch(void* const* d_in, const int* in_sizes, int n_in,
                              void* d_out, int out_size, void* d_ws, size_t ws_size,
                              hipStream_t stream)
{
    const float* x        = (const float*)d_in[0];
    const int*   ei       = (const int*)d_in[1];
    const float* ew       = (const float*)d_in[2];
    const float* w_gat    = (const float*)d_in[3];
    const float* att_src  = (const float*)d_in[4];
    const float* att_dst  = (const float*)d_in[5];
    const float* w_edge   = (const float*)d_in[6];
    const float* att_edge = (const float*)d_in[7];
    const float* b_gat    = (const float*)d_in[8];
    const float* w_gcn    = (const float*)d_in[9];
    const float* b_gcn    = (const float*)d_in[10];
    const float* w_out    = (const float*)d_in[11];
    const float* b_out    = (const float*)d_in[12];

    const int* src = ei;
    const int* dst = ei + N_EDGES;

    float* out_head  = (float*)d_out;
    float* out_ei    = out_head + 2 * N_NODES;
    float* out_alpha = out_ei + 2 * N_EDGES;

    char* ws = (char*)d_ws;
    size_t o = 0;
    auto alloc = [&](size_t bytes) -> char* {
        char* p = ws + o;
        o = (o + bytes + 255) & ~(size_t)255;
        return p;
    };
    float* agg       = (float*)alloc((size_t)N_NODES * HID * 4);  // 51.2 MB
    float* xagg      = (float*)alloc((size_t)N_NODES * D_IN * 4); // 2.4 MB
    float* a_src     = (float*)alloc(N_NODES * 4);
    float* a_dst     = (float*)alloc(N_NODES * 4);
    float* dinv      = (float*)alloc(N_NODES * 4);
    int*   cnt       = (int*)alloc(N_NODES * 4);
    int*   incl      = (int*)alloc(N_NODES * 4);
    int*   off       = (int*)alloc((N_NODES + 1) * 4);
    int*   fill      = (int*)alloc(N_NODES * 4);
    int*   bsums     = (int*)alloc(512 * 4);
    int*   boffs     = (int*)alloc(512 * 4);
    int*   src_srt   = (int*)alloc((size_t)N_EDGES * 4);
    int*   eid_srt   = (int*)alloc((size_t)N_EDGES * 4);
    float* logit_srt = (float*)alloc((size_t)N_EDGES * 4);
    float* alpha_srt = (float*)alloc((size_t)N_EDGES * 4);
    float* w_as      = (float*)alloc(D_IN * 4);
    float* w_ad      = (float*)alloc(D_IN * 4);
    float* dotwe     = (float*)alloc(4);
    (void)ws_size; (void)out_size; (void)n_in; (void)in_sizes;

    hipMemsetAsync(cnt, 0, N_NODES * 4, stream);
    hipMemsetAsync(fill, 0, N_NODES * 4, stream);

    const int NB_SCAN = (N_NODES + 255) / 256;  // 391

    k_prep<<<1, 128, 0, stream>>>(w_gat, att_src, att_dst, w_edge, att_edge,
                                  w_as, w_ad, dotwe);
    k_asrc<<<NB_SCAN, 256, 0, stream>>>(x, w_as, w_ad, a_src, a_dst);
    k_count<<<(N_EDGES + 255) / 256, 256, 0, stream>>>(dst, cnt);
    k_scan1<<<NB_SCAN, 256, 0, stream>>>(cnt, incl, bsums);
    k_scan2<<<1, 512, 0, stream>>>(bsums, boffs, NB_SCAN);
    k_scan3<<<NB_SCAN, 256, 0, stream>>>(cnt, incl, boffs, off);
    k_scatter<<<(N_EDGES + 255) / 256, 256, 0, stream>>>(
        src, dst, ew, a_src, a_dst, dotwe, off, fill, src_srt, eid_srt, logit_srt);
    k_soft<<<N_NODES / 4, 256, 0, stream>>>(
        src_srt, eid_srt, logit_srt, off, x, alpha_srt, out_alpha, dinv, xagg);
    k_gcn_gather<<<N_NODES, 256, 0, stream>>>(
        src_srt, off, alpha_srt, dinv, xagg, w_gat, b_gat, agg);
    k_dense2<<<N_NODES / NPB, 128, 0, stream>>>(
        agg, w_gcn, b_gcn, w_out, b_out, out_head);
    k_copy_ei<<<(2 * N_EDGES + 255) / 256, 256, 0, stream>>>(ei, out_ei);
}

// Round 3
// 473.331 us; speedup vs baseline: 1.7038x; 1.2029x over previous
//
#include <hip/hip_runtime.h>
#include <hip/hip_bf16.h>
#include <math.h>

#define N_NODES 100000
#define N_EDGES 1600000
#define HID 128
#define D_IN 6
#define NEG_SLOPE 0.2f

__device__ inline float wred_sum(float v) {
    for (int o = 32; o; o >>= 1) v += __shfl_xor(v, o);
    return v;
}
__device__ inline float wred_max(float v) {
    for (int o = 32; o; o >>= 1) v = fmaxf(v, __shfl_xor(v, o));
    return v;
}

// ---------------------------------------------------------------------------
// K_prep (1 block): w_as = w_gat@att_src (6), w_ad = w_gat@att_dst (6),
// dotwe = w_edge . att_edge
__global__ __launch_bounds__(128) void k_prep(
    const float* __restrict__ w_gat, const float* __restrict__ att_src,
    const float* __restrict__ att_dst, const float* __restrict__ w_edge,
    const float* __restrict__ att_edge, float* __restrict__ w_as,
    float* __restrict__ w_ad, float* __restrict__ dotwe)
{
    int tid = threadIdx.x;
    __shared__ float red[4];
    float as = att_src[tid], ad = att_dst[tid];

    float v = w_edge[tid] * att_edge[tid];
    for (int o = 32; o; o >>= 1) v += __shfl_down(v, o);
    if ((tid & 63) == 0) red[tid >> 6] = v;
    __syncthreads();
    if (tid == 0) dotwe[0] = red[0] + red[1];

#pragma unroll
    for (int i = 0; i < D_IN; ++i) {
        float wv = w_gat[i * HID + tid];
        float v1 = wv * as, v2 = wv * ad;
        for (int o = 32; o; o >>= 1) {
            v1 += __shfl_down(v1, o);
            v2 += __shfl_down(v2, o);
        }
        __syncthreads();
        if ((tid & 63) == 0) { red[(tid >> 6) * 2] = v1; red[(tid >> 6) * 2 + 1] = v2; }
        __syncthreads();
        if (tid == 0) { w_as[i] = red[0] + red[2]; w_ad[i] = red[1] + red[3]; }
    }
}

// ---------------------------------------------------------------------------
__global__ __launch_bounds__(256) void k_asrc(
    const float* __restrict__ x, const float* __restrict__ w_as,
    const float* __restrict__ w_ad, float* __restrict__ a_src,
    float* __restrict__ a_dst)
{
    int n = blockIdx.x * 256 + threadIdx.x;
    if (n >= N_NODES) return;
    float s0 = 0.f, s1 = 0.f;
#pragma unroll
    for (int i = 0; i < D_IN; ++i) {
        float xv = x[n * D_IN + i];
        s0 += xv * w_as[i];
        s1 += xv * w_ad[i];
    }
    a_src[n] = s0;
    a_dst[n] = s1;
}

// ---------------------------------------------------------------------------
__global__ __launch_bounds__(256) void k_count(
    const int* __restrict__ dst, int* __restrict__ cnt)
{
    int e = blockIdx.x * 256 + threadIdx.x;
    if (e < N_EDGES) atomicAdd(&cnt[dst[e]], 1);
}

// ---------------------------------------------------------------------------
__global__ __launch_bounds__(256) void k_scan1(
    const int* __restrict__ cnt, int* __restrict__ incl, int* __restrict__ bsums)
{
    __shared__ int s[256];
    int tid = threadIdx.x;
    int i = blockIdx.x * 256 + tid;
    int v = (i < N_NODES) ? cnt[i] : 0;
    s[tid] = v;
    __syncthreads();
    for (int o = 1; o < 256; o <<= 1) {
        int t = (tid >= o) ? s[tid - o] : 0;
        __syncthreads();
        s[tid] += t;
        __syncthreads();
    }
    if (i < N_NODES) incl[i] = s[tid];
    if (tid == 255) bsums[blockIdx.x] = s[255];
}

__global__ __launch_bounds__(512) void k_scan2(
    const int* __restrict__ bsums, int* __restrict__ boffs, int nb)
{
    __shared__ int s[512];
    int tid = threadIdx.x;
    int v = (tid < nb) ? bsums[tid] : 0;
    s[tid] = v;
    __syncthreads();
    for (int o = 1; o < 512; o <<= 1) {
        int t = (tid >= o) ? s[tid - o] : 0;
        __syncthreads();
        s[tid] += t;
        __syncthreads();
    }
    if (tid < nb) boffs[tid] = s[tid] - v;  // exclusive
}

__global__ __launch_bounds__(256) void k_scan3(
    const int* __restrict__ cnt, const int* __restrict__ incl,
    const int* __restrict__ boffs, int* __restrict__ off)
{
    int i = blockIdx.x * 256 + threadIdx.x;
    if (i < N_NODES) {
        int b = boffs[blockIdx.x];
        off[i] = b + incl[i] - cnt[i];
        if (i == N_NODES - 1) off[N_NODES] = b + incl[i];
    }
}

// ---------------------------------------------------------------------------
// K_scatter_perm: only writes the permutation (4B random/edge instead of 12B)
__global__ __launch_bounds__(256) void k_scatter_perm(
    const int* __restrict__ dst, const int* __restrict__ off,
    int* __restrict__ fill, int* __restrict__ perm)
{
    int e = blockIdx.x * 256 + threadIdx.x;
    if (e >= N_EDGES) return;
    int d = dst[e];
    int pos = off[d] + atomicAdd(&fill[d], 1);
    perm[pos] = e;
}

// ---------------------------------------------------------------------------
// K_soft: per-node (1 wave) register-resident segment softmax; produces
// coalesced src_srt/alpha_srt + original-order alpha_out + xagg8 {dinv,x0..5,0}
__global__ __launch_bounds__(256) void k_soft(
    const int* __restrict__ perm, const int* __restrict__ src,
    const float* __restrict__ ew, const float* __restrict__ a_src,
    const float* __restrict__ a_dst, const float* __restrict__ dotwe,
    const int* __restrict__ off, const float* __restrict__ x,
    float* __restrict__ alpha_srt, int* __restrict__ src_srt,
    float* __restrict__ alpha_out, float* __restrict__ xagg8)
{
    int n = blockIdx.x * 4 + (threadIdx.x >> 6);
    int l = threadIdx.x & 63;
    int beg = off[n], end = off[n + 1];
    float adn = a_dst[n];
    float dw = dotwe[0];

    // pass 1: logits + segment max (first 64 edges cached in registers)
    int e0 = -1, s0 = 0;
    float lg0 = 0.f;
    float m = -INFINITY;
    {
        int j = beg + l;
        if (j < end) {
            e0 = perm[j];
            s0 = src[e0];
            float lg = a_src[s0] + adn + dw * ew[e0];
            lg0 = (lg >= 0.f) ? lg : NEG_SLOPE * lg;
            m = lg0;
        }
        for (j = beg + l + 64; j < end; j += 64) {
            int e = perm[j];
            int s = src[e];
            float lg = a_src[s] + adn + dw * ew[e];
            lg = (lg >= 0.f) ? lg : NEG_SLOPE * lg;
            m = fmaxf(m, lg);
        }
    }
    m = wred_max(m);

    // pass 2: exp + sum
    float p0 = 0.f, ps = 0.f;
    if (e0 >= 0) { p0 = __expf(lg0 - m); ps = p0; }
    for (int j = beg + l + 64; j < end; j += 64) {
        int e = perm[j];
        int s = src[e];
        float lg = a_src[s] + adn + dw * ew[e];
        lg = (lg >= 0.f) ? lg : NEG_SLOPE * lg;
        ps += __expf(lg - m);
    }
    ps = wred_sum(ps);
    float scale = 1.0f / fmaxf(ps, 1e-16f);

    // pass 3: normalize, write outputs, accumulate 6-dim weighted x
    float ax0 = 0, ax1 = 0, ax2 = 0, ax3 = 0, ax4 = 0, ax5 = 0;
    if (e0 >= 0) {
        float a = p0 * scale;
        alpha_out[e0] = a;
        alpha_srt[beg + l] = a;
        src_srt[beg + l] = s0;
        const float2* xp = (const float2*)(x + (size_t)s0 * D_IN);
        float2 q0 = xp[0], q1 = xp[1], q2 = xp[2];
        ax0 = a * q0.x; ax1 = a * q0.y; ax2 = a * q1.x;
        ax3 = a * q1.y; ax4 = a * q2.x; ax5 = a * q2.y;
    }
    for (int j = beg + l + 64; j < end; j += 64) {
        int e = perm[j];
        int s = src[e];
        float lg = a_src[s] + adn + dw * ew[e];
        lg = (lg >= 0.f) ? lg : NEG_SLOPE * lg;
        float a = __expf(lg - m) * scale;
        alpha_out[e] = a;
        alpha_srt[j] = a;
        src_srt[j] = s;
        const float2* xp = (const float2*)(x + (size_t)s * D_IN);
        float2 q0 = xp[0], q1 = xp[1], q2 = xp[2];
        ax0 += a * q0.x; ax1 += a * q0.y; ax2 += a * q1.x;
        ax3 += a * q1.y; ax4 += a * q2.x; ax5 += a * q2.y;
    }
    ax0 = wred_sum(ax0); ax1 = wred_sum(ax1); ax2 = wred_sum(ax2);
    ax3 = wred_sum(ax3); ax4 = wred_sum(ax4); ax5 = wred_sum(ax5);
    if (l == 0) {
        // sum(alpha) over a non-empty segment == 1 -> dinv == 1 (err ~1e-7)
        float dv = (end > beg) ? 1.0f : 0.0f;
        float* xo = xagg8 + (size_t)n * 8;
        xo[0] = dv;  xo[1] = ax0; xo[2] = ax1; xo[3] = ax2;
        xo[4] = ax3; xo[5] = ax4; xo[6] = ax5; xo[7] = 0.f;
    }
}

// ---------------------------------------------------------------------------
// K_gcn_gather (2-phase): 4 nodes/block.
// P1: lane-per-edge parallel gather of {dinv_s*alpha, xagg[0..5]} -> LDS.
// P2: wave-per-node, 2 features/lane, broadcast ds_read_b128, per-feature acc
// (no reduce epilogue); dinv[n] applied at the end.
#define GCAP 128
__global__ __launch_bounds__(256) void k_gcn_gather(
    const int* __restrict__ src_srt, const int* __restrict__ off,
    const float* __restrict__ alpha_srt, const float* __restrict__ xagg8,
    const float* __restrict__ w_gat, const float* __restrict__ b_gat,
    float* __restrict__ agg)
{
    __shared__ float lds[GCAP * 12];   // stride 12 floats: f4-aligned, 2-way banks
    int tid = threadIdx.x;
    int n0 = blockIdx.x * 4;
    int wid = tid >> 6, l = tid & 63;
    int n = n0 + wid;
    int beg0 = off[n0];
    int total = off[n0 + 4] - beg0;
    int nb = off[n] - beg0, ne = off[n + 1] - beg0;

    int kA = l, kB = l + 64;
    float wA0 = w_gat[0 * HID + kA], wA1 = w_gat[1 * HID + kA], wA2 = w_gat[2 * HID + kA];
    float wA3 = w_gat[3 * HID + kA], wA4 = w_gat[4 * HID + kA], wA5 = w_gat[5 * HID + kA];
    float wB0 = w_gat[0 * HID + kB], wB1 = w_gat[1 * HID + kB], wB2 = w_gat[2 * HID + kB];
    float wB3 = w_gat[3 * HID + kB], wB4 = w_gat[4 * HID + kB], wB5 = w_gat[5 * HID + kB];
    float bA = b_gat[kA], bB = b_gat[kB];
    float accA = 0.f, accB = 0.f;

    for (int base = 0; base < total; base += GCAP) {
        int cnt = min(GCAP, total - base);
        __syncthreads();
        if (tid < cnt) {
            int j = beg0 + base + tid;
            int s = src_srt[j];              // coalesced
            float a = alpha_srt[j];          // coalesced
            const float4* xp = (const float4*)(xagg8 + (size_t)s * 8);
            float4 lo = xp[0], hi = xp[1];   // {dinv_s,x0,x1,x2},{x3,x4,x5,-}
            float4 w0 = {lo.x * a, lo.y, lo.z, lo.w};
            float4 w1 = {hi.x, hi.y, hi.z, 0.f};
            *(float4*)(lds + tid * 12) = w0;
            *(float4*)(lds + tid * 12 + 4) = w1;
        }
        __syncthreads();
        int lo_t = nb - base; if (lo_t < 0) lo_t = 0;
        int hi_t = ne - base; if (hi_t > cnt) hi_t = cnt;
        for (int t = lo_t; t < hi_t; ++t) {
            float4 e0 = *(const float4*)(lds + t * 12);
            float4 e1 = *(const float4*)(lds + t * 12 + 4);
            float hA = bA, hB = bB;
            hA = fmaf(e0.y, wA0, hA); hB = fmaf(e0.y, wB0, hB);
            hA = fmaf(e0.z, wA1, hA); hB = fmaf(e0.z, wB1, hB);
            hA = fmaf(e0.w, wA2, hA); hB = fmaf(e0.w, wB2, hB);
            hA = fmaf(e1.x, wA3, hA); hB = fmaf(e1.x, wB3, hB);
            hA = fmaf(e1.y, wA4, hA); hB = fmaf(e1.y, wB4, hB);
            hA = fmaf(e1.z, wA5, hA); hB = fmaf(e1.z, wB5, hB);
            hA = fmaxf(hA, 0.f); hB = fmaxf(hB, 0.f);
            accA = fmaf(e0.x, hA, accA); accB = fmaf(e0.x, hB, accB);
        }
    }
    float dn = xagg8[(size_t)n * 8];
    agg[(size_t)n * HID + kA] = dn * accA;
    agg[(size_t)n * HID + kB] = dn * accB;
}

// ---------------------------------------------------------------------------
// K_dense2: h2 = relu(agg @ w_gcn + b_gcn); out = h2 @ w_out + b_out
#define NPB 32
#define HSTR (NPB + 4)
__global__ __launch_bounds__(128) void k_dense2(
    const float* __restrict__ agg, const float* __restrict__ w_gcn,
    const float* __restrict__ b_gcn, const float* __restrict__ w_out,
    const float* __restrict__ b_out, float* __restrict__ out)
{
    __shared__ float hsT[HID][HSTR];
    __shared__ float red[2][64];
    int n0 = blockIdx.x * NPB;
    int tid = threadIdx.x;

#pragma unroll
    for (int r = 0; r < NPB; ++r)
        hsT[tid][r] = agg[(size_t)(n0 + r) * HID + tid];
    __syncthreads();

    float acc[NPB];
#pragma unroll
    for (int r = 0; r < NPB; ++r) acc[r] = 0.f;
    for (int i = 0; i < HID; ++i) {
        float wv = w_gcn[i * HID + tid];
        const float4* hp = (const float4*)&hsT[i][0];
#pragma unroll
        for (int r4 = 0; r4 < NPB / 4; ++r4) {
            float4 hv = hp[r4];
            acc[r4 * 4 + 0] += hv.x * wv;
            acc[r4 * 4 + 1] += hv.y * wv;
            acc[r4 * 4 + 2] += hv.z * wv;
            acc[r4 * 4 + 3] += hv.w * wv;
        }
    }
    __syncthreads();

    float b = b_gcn[tid];
#pragma unroll
    for (int r = 0; r < NPB; ++r)
        hsT[tid][r] = fmaxf(acc[r] + b, 0.f);   // h2, transposed
    __syncthreads();

    int r = tid & 31, o = (tid >> 5) & 1, half = tid >> 6;
    float v = 0.f;
    for (int k = half * 64; k < half * 64 + 64; ++k)
        v += hsT[k][r] * w_out[k * 2 + o];
    red[half][tid & 63] = v;
    __syncthreads();
    if (tid < 64) {
        float t = red[0][tid] + red[1][tid];
        int rr = tid & 31, oo = tid >> 5;
        out[(size_t)(n0 + rr) * 2 + oo] = t + b_out[oo];
    }
}

// ---------------------------------------------------------------------------
__global__ __launch_bounds__(256) void k_copy_ei(
    const int* __restrict__ ei, float* __restrict__ out_ei)
{
    int i = blockIdx.x * 256 + threadIdx.x;
    if (i < 2 * N_EDGES) out_ei[i] = (float)ei[i];
}

// ---------------------------------------------------------------------------
extern "C" void kernel_launch(void* const* d_in, const int* in_sizes, int n_in,
                              void* d_out, int out_size, void* d_ws, size_t ws_size,
                              hipStream_t stream)
{
    const float* x        = (const float*)d_in[0];
    const int*   ei       = (const int*)d_in[1];
    const float* ew       = (const float*)d_in[2];
    const float* w_gat    = (const float*)d_in[3];
    const float* att_src  = (const float*)d_in[4];
    const float* att_dst  = (const float*)d_in[5];
    const float* w_edge   = (const float*)d_in[6];
    const float* att_edge = (const float*)d_in[7];
    const float* b_gat    = (const float*)d_in[8];
    const float* w_gcn    = (const float*)d_in[9];
    const float* b_gcn    = (const float*)d_in[10];
    const float* w_out    = (const float*)d_in[11];
    const float* b_out    = (const float*)d_in[12];

    const int* src = ei;
    const int* dst = ei + N_EDGES;

    float* out_head  = (float*)d_out;
    float* out_ei    = out_head + 2 * N_NODES;
    float* out_alpha = out_ei + 2 * N_EDGES;

    char* ws = (char*)d_ws;
    size_t o = 0;
    auto alloc = [&](size_t bytes) -> char* {
        char* p = ws + o;
        o = (o + bytes + 255) & ~(size_t)255;
        return p;
    };
    float* agg       = (float*)alloc((size_t)N_NODES * HID * 4);   // 51.2 MB
    float* xagg8     = (float*)alloc((size_t)N_NODES * 8 * 4);     // 3.2 MB
    float* a_src     = (float*)alloc(N_NODES * 4);
    float* a_dst     = (float*)alloc(N_NODES * 4);
    int*   cnt       = (int*)alloc(N_NODES * 4);
    int*   incl      = (int*)alloc(N_NODES * 4);
    int*   off       = (int*)alloc((N_NODES + 1) * 4);
    int*   fill      = (int*)alloc(N_NODES * 4);
    int*   bsums     = (int*)alloc(512 * 4);
    int*   boffs     = (int*)alloc(512 * 4);
    int*   perm      = (int*)alloc((size_t)N_EDGES * 4);
    int*   src_srt   = (int*)alloc((size_t)N_EDGES * 4);
    float* alpha_srt = (float*)alloc((size_t)N_EDGES * 4);
    float* w_as      = (float*)alloc(D_IN * 4);
    float* w_ad      = (float*)alloc(D_IN * 4);
    float* dotwe     = (float*)alloc(4);
    (void)ws_size; (void)out_size; (void)n_in; (void)in_sizes;

    hipMemsetAsync(cnt, 0, N_NODES * 4, stream);
    hipMemsetAsync(fill, 0, N_NODES * 4, stream);

    const int NB_SCAN = (N_NODES + 255) / 256;  // 391

    k_prep<<<1, 128, 0, stream>>>(w_gat, att_src, att_dst, w_edge, att_edge,
                                  w_as, w_ad, dotwe);
    k_asrc<<<NB_SCAN, 256, 0, stream>>>(x, w_as, w_ad, a_src, a_dst);
    k_count<<<(N_EDGES + 255) / 256, 256, 0, stream>>>(dst, cnt);
    k_scan1<<<NB_SCAN, 256, 0, stream>>>(cnt, incl, bsums);
    k_scan2<<<1, 512, 0, stream>>>(bsums, boffs, NB_SCAN);
    k_scan3<<<NB_SCAN, 256, 0, stream>>>(cnt, incl, boffs, off);
    k_scatter_perm<<<(N_EDGES + 255) / 256, 256, 0, stream>>>(dst, off, fill, perm);
    k_soft<<<N_NODES / 4, 256, 0, stream>>>(
        perm, src, ew, a_src, a_dst, dotwe, off, x,
        alpha_srt, src_srt, out_alpha, xagg8);
    k_gcn_gather<<<N_NODES / 4, 256, 0, stream>>>(
        src_srt, off, alpha_srt, xagg8, w_gat, b_gat, agg);
    k_dense2<<<N_NODES / NPB, 128, 0, stream>>>(
        agg, w_gcn, b_gcn, w_out, b_out, out_head);
    k_copy_ei<<<(2 * N_EDGES + 255) / 256, 256, 0, stream>>>(ei, out_ei);
}